// Round 3
// baseline (5130.930 us; speedup 1.0000x reference)
//
#include <hip/hip_runtime.h>
#include <hip/hip_bf16.h>
#include <hip/hip_fp16.h>
#include <cstdint>

// ---------------------------------------------------------------------------
// RWKV6 attention, f32-compute / f16-stream implementation.
//   d_out is reused as rotating f32 scratch: xw -> inb(x5) -> o -> final out.
//   d_ws holds: z(f32), w1(f32), r/k/w/v/g (f16), yb(f32, overlaps r..v).
//   Total d_ws need: ~127 MiB (known to fit; bf16->f16 keeps size, 8x accuracy).
// ---------------------------------------------------------------------------

#define GBM 128
#define GBN 128
#define GBK 16
#define GPAD 4  // LDS row stride 132 floats

__device__ __forceinline__ float h2f(const __half h) { return __half2float(h); }
__device__ __forceinline__ unsigned short f2h(float f) {
    __half h = __float2half(f);
    return *reinterpret_cast<unsigned short*>(&h);
}

__global__ __launch_bounds__(256, 2) void gemm_bt(
    const float* __restrict__ A, int lda,
    const float* __restrict__ W, int ldw,
    void* __restrict__ Cv, int ldc,
    int M, int N, int Kd,
    const float* __restrict__ bias,
    int act,   // 0 none, 1 tanh
    int mode,  // 0 plain, 1 delta-lerp: C = x + (x_prev - x) * val  (f32 out)
    int ohalf, // 0 f32 out, 1 f16 out
    const float* __restrict__ X, int T)
{
    __shared__ float As[GBK][GBM + GPAD];
    __shared__ float Ws[GBK][GBN + GPAD];
    const int tid = threadIdx.x;
    const int m0 = blockIdx.y * GBM;
    const int n0 = blockIdx.x * GBN;
    const int tm = tid >> 4, tn = tid & 15;

    float acc[8][8];
#pragma unroll
    for (int i = 0; i < 8; i++)
#pragma unroll
        for (int j = 0; j < 8; j++) acc[i][j] = 0.f;

    const int lm = tid >> 2;        // 0..63
    const int lk = (tid & 3) * 4;   // 0,4,8,12

    for (int k0 = 0; k0 < Kd; k0 += GBK) {
#pragma unroll
        for (int half = 0; half < 2; ++half) {
            const int row = lm + half * 64;
            const float4 va = *(const float4*)(A + (size_t)(m0 + row) * lda + k0 + lk);
            As[lk + 0][row] = va.x; As[lk + 1][row] = va.y;
            As[lk + 2][row] = va.z; As[lk + 3][row] = va.w;
            const int wrow = n0 + row;
            float4 vw = make_float4(0.f, 0.f, 0.f, 0.f);
            if (wrow < N) vw = *(const float4*)(W + (size_t)wrow * ldw + k0 + lk);
            Ws[lk + 0][row] = vw.x; Ws[lk + 1][row] = vw.y;
            Ws[lk + 2][row] = vw.z; Ws[lk + 3][row] = vw.w;
        }
        __syncthreads();
#pragma unroll
        for (int kk = 0; kk < GBK; ++kk) {
            const float4 a0 = *(const float4*)&As[kk][tm * 8];
            const float4 a1 = *(const float4*)&As[kk][tm * 8 + 4];
            const float4 b0 = *(const float4*)&Ws[kk][tn * 8];
            const float4 b1 = *(const float4*)&Ws[kk][tn * 8 + 4];
            const float av[8] = {a0.x, a0.y, a0.z, a0.w, a1.x, a1.y, a1.z, a1.w};
            const float bv[8] = {b0.x, b0.y, b0.z, b0.w, b1.x, b1.y, b1.z, b1.w};
#pragma unroll
            for (int i = 0; i < 8; i++)
#pragma unroll
                for (int j = 0; j < 8; j++)
                    acc[i][j] = fmaf(av[i], bv[j], acc[i][j]);
        }
        __syncthreads();
    }

#pragma unroll
    for (int i = 0; i < 8; i++) {
        const int gm = m0 + tm * 8 + i;
        const int trow = gm % T;
#pragma unroll
        for (int j4 = 0; j4 < 2; j4++) {
            const int gn0 = n0 + tn * 8 + j4 * 4;
            if (gn0 >= N) continue;  // N is always a multiple of 4
            float4 v4;
            float* vp = &v4.x;
#pragma unroll
            for (int c = 0; c < 4; c++) {
                float a = acc[i][j4 * 4 + c];
                if (bias) a += bias[gn0 + c];
                if (act == 1) a = tanhf(a);
                vp[c] = a;
            }
            if (mode == 1) {
                float* C = (float*)Cv;
                const float4 xv = *(const float4*)(X + (size_t)gm * 1024 + gn0);
                float4 xp = make_float4(0.f, 0.f, 0.f, 0.f);
                if (trow) xp = *(const float4*)(X + (size_t)(gm - 1) * 1024 + gn0);
                v4.x = xv.x + (xp.x - xv.x) * v4.x;
                v4.y = xv.y + (xp.y - xv.y) * v4.y;
                v4.z = xv.z + (xp.z - xv.z) * v4.z;
                v4.w = xv.w + (xp.w - xv.w) * v4.w;
                *(float4*)(C + (size_t)gm * ldc + gn0) = v4;
            } else if (ohalf) {
                __half* C = (__half*)Cv;
                ushort4 u;
                u.x = f2h(v4.x); u.y = f2h(v4.y);
                u.z = f2h(v4.z); u.w = f2h(v4.w);
                *(ushort4*)(C + (size_t)gm * ldc + gn0) = u;
            } else {
                float* C = (float*)Cv;
                *(float4*)(C + (size_t)gm * ldc + gn0) = v4;
            }
        }
    }
}

// token shift for x_proj: xw = x + (x_prev - x) * mu_x
__global__ void k_xw(const float* __restrict__ X, const float* __restrict__ mu,
                     float* __restrict__ XW, int M, int T)
{
    const size_t i4 = (size_t)blockIdx.x * blockDim.x + threadIdx.x;
    if (i4 >= (size_t)M * 256) return;
    const size_t idx = i4 * 4;
    const int m = (int)(idx >> 10);
    const int d = (int)(idx & 1023);
    const int t = m % T;
    const float4 xv = *(const float4*)(X + idx);
    const float4 m4 = *(const float4*)(mu + d);
    float4 xp = make_float4(0.f, 0.f, 0.f, 0.f);
    if (t > 0) xp = *(const float4*)(X + idx - 1024);
    float4 o;
    o.x = xv.x + (xp.x - xv.x) * m4.x;
    o.y = xv.y + (xp.y - xv.y) * m4.y;
    o.z = xv.z + (xp.z - xv.z) * m4.z;
    o.w = xv.w + (xp.w - xv.w) * m4.w;
    *(float4*)(XW + idx) = o;
}

// Recurrence: grid = B*Hh*4 blocks (vb = 64-column slice of V=256).
// 256 threads = 4 waves; wave w owns k in [32w, 32w+32), lane = v column.
// State S[32] per thread in registers. Double-buffered LDS staging.
__global__ __launch_bounds__(256) void rwkv_rec(
    const __half* __restrict__ R, const __half* __restrict__ Kk,
    const __half* __restrict__ Wr, const __half* __restrict__ Vv,
    const float* __restrict__ bonus, float* __restrict__ O, int T)
{
    __shared__ float4 s4[2][128];      // {r, k, decay, r*u*k}
    __shared__ float svv[2][64];
    __shared__ float opart[2][4][64];

    const int bid = blockIdx.x;
    const int b = bid >> 4;
    const int h = (bid >> 2) & 3;
    const int vb = bid & 3;
    const int tid = threadIdx.x;
    const int wave = tid >> 6, lane = tid & 63;

    const size_t tok0 = (size_t)b * T;
    const __half* Rp = R + tok0 * 512 + h * 128;
    const __half* Kp = Kk + tok0 * 512 + h * 128;
    const __half* Wp = Wr + tok0 * 512 + h * 128;
    const __half* Vp = Vv + tok0 * 1024 + h * 256 + vb * 64;
    float* Op = O + tok0 * 1024 + h * 256 + vb * 64;

    const float u_reg = (tid < 128) ? bonus[h * 128 + tid] : 0.f;
    float S[32];
#pragma unroll
    for (int j = 0; j < 32; j++) S[j] = 0.f;
    const int kbase = wave * 32;

    float lr = 0.f, lk2 = 0.f, lw = 0.f, lv = 0.f;
    if (tid < 128) {
        const float rv = h2f(Rp[tid]), kv = h2f(Kp[tid]), wv = h2f(Wp[tid]);
        s4[0][tid] = make_float4(rv, kv, __expf(-__expf(wv)), rv * u_reg * kv);
    }
    if (tid < 64) svv[0][tid] = h2f(Vp[tid]);
    if (T > 1) {
        if (tid < 128) { lr = h2f(Rp[512 + tid]); lk2 = h2f(Kp[512 + tid]); lw = h2f(Wp[512 + tid]); }
        if (tid < 64) lv = h2f(Vp[1024 + tid]);
    }
    __syncthreads();

    for (int t = 0; t < T; ++t) {
        const int cur = t & 1, nxt = cur ^ 1;
        if (t + 1 < T) {
            if (tid < 128)
                s4[nxt][tid] = make_float4(lr, lk2, __expf(-__expf(lw)), lr * u_reg * lk2);
            if (tid < 64) svv[nxt][tid] = lv;
        }
        if (t + 2 < T) {
            const size_t off = (size_t)(t + 2) * 512 + tid;
            if (tid < 128) { lr = h2f(Rp[off]); lk2 = h2f(Kp[off]); lw = h2f(Wp[off]); }
            if (tid < 64) lv = h2f(Vp[(size_t)(t + 2) * 1024 + tid]);
        }
        const float vv = svv[cur][lane];
        float osum = 0.f, rusum = 0.f;
#pragma unroll
        for (int j = 0; j < 32; j++) {
            const float4 q = s4[cur][kbase + j];
            osum = fmaf(q.x, S[j], osum);      // r_k * S_{t-1}[k,v]
            rusum += q.w;                      // sum r*u*k
            S[j] = fmaf(q.z, S[j], q.y * vv);  // S = decay*S + k*v
        }
        osum = fmaf(rusum, vv, osum);
        opart[cur][wave][lane] = osum;
        if (t > 0 && wave == 0) {
            const float oo = opart[nxt][0][lane] + opart[nxt][1][lane] +
                             opart[nxt][2][lane] + opart[nxt][3][lane];
            Op[(size_t)(t - 1) * 1024 + lane] = oo;
        }
        __syncthreads();
    }
    if (wave == 0) {
        const int c = (T - 1) & 1;
        const float oo = opart[c][0][lane] + opart[c][1][lane] +
                         opart[c][2][lane] + opart[c][3][lane];
        Op[(size_t)(T - 1) * 1024 + lane] = oo;
    }
}

// GroupNorm(4 heads x 256) + affine + silu(g) gate. 1 block per token, wave per head.
__global__ __launch_bounds__(256) void gn_gate(
    const float* __restrict__ Obuf, const __half* __restrict__ G,
    const float* __restrict__ gnw, const float* __restrict__ gnb,
    float* __restrict__ Y)
{
    const int token = blockIdx.x;
    const int wave = threadIdx.x >> 6, lane = threadIdx.x & 63;
    const size_t base = (size_t)token * 1024 + wave * 256 + lane * 4;
    const float4 x = *(const float4*)(Obuf + base);
    float sum = x.x + x.y + x.z + x.w;
    float ssq = x.x * x.x + x.y * x.y + x.z * x.z + x.w * x.w;
#pragma unroll
    for (int off = 32; off >= 1; off >>= 1) {
        sum += __shfl_xor(sum, off);
        ssq += __shfl_xor(ssq, off);
    }
    const float mean = sum * (1.f / 256.f);
    const float var = ssq * (1.f / 256.f) - mean * mean;
    const float rstd = rsqrtf(var + 1e-5f);
    const int c0 = wave * 256 + lane * 4;
    const float4 w4 = *(const float4*)(gnw + c0);
    const float4 b4 = *(const float4*)(gnb + c0);
    const ushort4 gu = *(const ushort4*)(G + base);
    const float g0 = __half2float(*reinterpret_cast<const __half*>(&gu.x));
    const float g1 = __half2float(*reinterpret_cast<const __half*>(&gu.y));
    const float g2 = __half2float(*reinterpret_cast<const __half*>(&gu.z));
    const float g3 = __half2float(*reinterpret_cast<const __half*>(&gu.w));
    float4 y;
    y.x = ((x.x - mean) * rstd * w4.x + b4.x) * (g0 / (1.f + __expf(-g0)));
    y.y = ((x.y - mean) * rstd * w4.y + b4.y) * (g1 / (1.f + __expf(-g1)));
    y.z = ((x.z - mean) * rstd * w4.z + b4.z) * (g2 / (1.f + __expf(-g2)));
    y.w = ((x.w - mean) * rstd * w4.w + b4.w) * (g3 / (1.f + __expf(-g3)));
    *(float4*)(Y + base) = y;
}

extern "C" void kernel_launch(void* const* d_in, const int* in_sizes, int n_in,
                              void* d_out, int out_size, void* d_ws, size_t ws_size,
                              hipStream_t stream)
{
    (void)in_sizes; (void)n_in; (void)out_size; (void)ws_size;
    const float* x      = (const float*)d_in[0];
    const float* mu_x   = (const float*)d_in[1];
    const float* W_x1   = (const float*)d_in[2];
    const float* W_x2   = (const float*)d_in[3];
    const float* x_bias = (const float*)d_in[4];
    const float* W_r    = (const float*)d_in[5];
    const float* W_k    = (const float*)d_in[6];
    const float* W_v    = (const float*)d_in[7];
    const float* W_g    = (const float*)d_in[8];
    const float* A_w    = (const float*)d_in[9];
    const float* B_w    = (const float*)d_in[10];
    const float* b_w    = (const float*)d_in[11];
    const float* bonus  = (const float*)d_in[12];
    const float* gnw    = (const float*)d_in[13];
    const float* gnb    = (const float*)d_in[14];
    const float* W_o    = (const float*)d_in[15];

    const int B = 8, T = 2048, M = B * T;

    // d_out doubles as rotating f32 scratch: xw -> inb(x5) -> o -> final out.
    float* dscratch = (float*)d_out;

    // d_ws layout (bytes):
    //   z  f32 M*160      @ 0
    //   w1 f32 M*64       @ M*640
    //   rb f16 M*512      @ M*896
    //   kb f16 M*512      @ +M*1024
    //   wr f16 M*512      @ +M*1024
    //   vb f16 M*1024     @ +M*1024
    //   gb f16 M*1024     @ +M*2048
    //   yb f32 M*1024 overlaps rb..vb (dead after recurrence)
    char* wsb = (char*)d_ws;
    float* z  = (float*)wsb;
    float* w1 = (float*)(wsb + (size_t)M * 640);
    __half* rb = (__half*)(wsb + (size_t)M * 896);
    __half* kb = rb + (size_t)M * 512;
    __half* wr = kb + (size_t)M * 512;
    __half* vb = wr + (size_t)M * 512;
    __half* gb = vb + (size_t)M * 1024;
    float* yb = (float*)rb;

    const dim3 blk(256);
    auto grid = [&](int N) { return dim3((N + GBN - 1) / GBN, M / GBM); };

    // 1. xw = x + delta*mu_x   (into d_out)
    k_xw<<<(M * 256 + 255) / 256, blk, 0, stream>>>(x, mu_x, dscratch, M, T);

    // 2. z = tanh(xw @ W_x1^T)
    gemm_bt<<<grid(160), blk, 0, stream>>>(dscratch, 1024, W_x1, 1024, z, 160,
                                           M, 160, 1024, nullptr, 1, 0, 0, nullptr, T);

    // 3. per-branch: inb = x + delta*(z_n @ W_x2_n^T + bias_n)  (into d_out),
    //    then the big projection GEMM (f16 out).
    const float* bigW[5] = {W_r, A_w, W_k, W_v, W_g};
    const int bigN[5]    = {512, 64, 512, 1024, 1024};
    for (int n = 0; n < 5; ++n) {
        gemm_bt<<<grid(1024), blk, 0, stream>>>(z + n * 32, 160, W_x2 + n * 32, 160,
                                                dscratch, 1024, M, 1024, 32,
                                                x_bias + n * 1024, 0, 1, 0, x, T);
        if (n == 1) {
            // w1 = tanh(inb @ A_w^T)  (f32), then wraw = w1 @ B_w^T + b_w (f16)
            gemm_bt<<<grid(64), blk, 0, stream>>>(dscratch, 1024, A_w, 1024, w1, 64,
                                                  M, 64, 1024, nullptr, 1, 0, 0, nullptr, T);
            gemm_bt<<<grid(512), blk, 0, stream>>>(w1, 64, B_w, 64, wr, 512,
                                                   M, 512, 64, b_w, 0, 0, 1, nullptr, T);
        } else {
            void* Cp = (n == 0) ? (void*)rb : (n == 2) ? (void*)kb
                     : (n == 3) ? (void*)vb : (void*)gb;
            gemm_bt<<<grid(bigN[n]), blk, 0, stream>>>(dscratch, 1024, bigW[n], 1024,
                                                       Cp, bigN[n], M, bigN[n], 1024,
                                                       nullptr, 0, 0, 1, nullptr, T);
        }
    }

    // 4. sequential recurrence (o into d_out)
    rwkv_rec<<<dim3(128), blk, 0, stream>>>(rb, kb, wr, vb, bonus, dscratch, T);

    // 5. groupnorm + silu gate (y into ws, reusing dead r/k/w/v region)
    gn_gate<<<dim3(M), blk, 0, stream>>>(dscratch, gb, gnw, gnb, yb);

    // 6. out = y @ W_o^T  (into d_out)
    gemm_bt<<<grid(1024), blk, 0, stream>>>(yb, 1024, W_o, 1024, d_out, 1024,
                                            M, 1024, 1024, nullptr, 0, 0, 0, nullptr, T);
}

// Round 4
// 2999.916 us; speedup vs baseline: 1.7104x; 1.7104x over previous
//
#include <hip/hip_runtime.h>
#include <hip/hip_bf16.h>
#include <hip/hip_fp16.h>
#include <cstdint>

// ---------------------------------------------------------------------------
// RWKV6 attention: f16-MFMA GEMMs + barrier-free register-state scan.
//   d_out rotates: [xw_h | inb_h] (f16) -> E (packed scan input) -> final f32.
//   ws: z,w1,r,k,w,v,g (f16), ru (f32), f16 weight copies; o_h/yb overlay
//   dead stream regions. Total ws ~= 128.7 MB.
// ---------------------------------------------------------------------------

typedef _Float16 half8 __attribute__((ext_vector_type(8)));
typedef float f32x4 __attribute__((ext_vector_type(4)));
typedef unsigned short ushort8 __attribute__((ext_vector_type(8)));

__device__ __forceinline__ float hbits2f(unsigned short us) {
    __half h; *reinterpret_cast<unsigned short*>(&h) = us; return __half2float(h);
}
__device__ __forceinline__ unsigned short f2h(float f) {
    __half h = __float2half(f);
    return *reinterpret_cast<unsigned short*>(&h);
}
__device__ __forceinline__ float2 up2(unsigned int u) {
    return make_float2(hbits2f((unsigned short)(u & 0xFFFF)),
                       hbits2f((unsigned short)(u >> 16)));
}

// ---------------- generic f32 -> f16 cast (weights) -------------------------
__global__ void cast16(const float* __restrict__ src, __half* __restrict__ dst, int n4)
{
    const int i = blockIdx.x * blockDim.x + threadIdx.x;
    if (i >= n4) return;
    const float4 f = *(const float4*)(src + (size_t)i * 4);
    ushort4 u;
    u.x = f2h(f.x); u.y = f2h(f.y); u.z = f2h(f.z); u.w = f2h(f.w);
    *(ushort4*)(dst + (size_t)i * 4) = u;
}

// ---------------- token shift (f16 out) -------------------------------------
__global__ void k_xw_h(const float* __restrict__ X, const float* __restrict__ mu,
                       __half* __restrict__ XW, int M, int T)
{
    const size_t i4 = (size_t)blockIdx.x * blockDim.x + threadIdx.x;
    if (i4 >= (size_t)M * 256) return;
    const size_t idx = i4 * 4;
    const int m = (int)(idx >> 10);
    const int d = (int)(idx & 1023);
    const int t = m & (T - 1);
    const float4 xv = *(const float4*)(X + idx);
    const float4 m4 = *(const float4*)(mu + d);
    float4 xp = make_float4(0.f, 0.f, 0.f, 0.f);
    if (t > 0) xp = *(const float4*)(X + idx - 1024);
    ushort4 o;
    o.x = f2h(xv.x + (xp.x - xv.x) * m4.x);
    o.y = f2h(xv.y + (xp.y - xv.y) * m4.y);
    o.z = f2h(xv.z + (xp.z - xv.z) * m4.z);
    o.w = f2h(xv.w + (xp.w - xv.w) * m4.w);
    *(ushort4*)(XW + idx) = o;
}

// ---------------- f16 MFMA GEMM: C[M,N] = A[M,K] @ B[N,K]^T -----------------
// epi: 0 f16 plain, 1 f16 tanh, 2 f16 bias+delta-lerp(X), 3 f16 bias, 4 f32 plain
#define TS 40  // LDS row stride in halfs (padded from 32)

__global__ __launch_bounds__(256) void gemm16(
    const __half* __restrict__ A, int lda,
    const __half* __restrict__ B, int ldb,
    void* __restrict__ Cv, int ldc,
    int M, int N, int K,
    const float* __restrict__ bias, int epi,
    const float* __restrict__ X, int T)
{
    __shared__ __align__(16) _Float16 As[128 * TS];
    __shared__ __align__(16) _Float16 Bs[128 * TS];

    const int tid = threadIdx.x;
    const int m0 = blockIdx.y * 128;
    const int n0 = blockIdx.x * 128;
    const int wave = tid >> 6, lane = tid & 63;
    const int wm = wave >> 1, wn = wave & 1;
    const int lr = lane & 15, lk = lane >> 4;

    const int srow = tid >> 1;          // 0..127
    const int sseg = (tid & 1) * 16;    // 0 or 16 halfs

    f32x4 acc[4][4] = {};

    for (int k0 = 0; k0 < K; k0 += 32) {
        // global loads (regs)
        const __half* ap = A + (size_t)(m0 + srow) * lda + k0 + sseg;
        ushort8 a0 = *(const ushort8*)ap;
        ushort8 a1 = *(const ushort8*)(ap + 8);
        ushort8 b0 = {0,0,0,0,0,0,0,0}, b1 = {0,0,0,0,0,0,0,0};
        if (n0 + srow < N) {
            const __half* bp = B + (size_t)(n0 + srow) * ldb + k0 + sseg;
            b0 = *(const ushort8*)bp;
            b1 = *(const ushort8*)(bp + 8);
        }
        __syncthreads();
        *(ushort8*)&As[srow * TS + sseg + 0] = a0;
        *(ushort8*)&As[srow * TS + sseg + 8] = a1;
        *(ushort8*)&Bs[srow * TS + sseg + 0] = b0;
        *(ushort8*)&Bs[srow * TS + sseg + 8] = b1;
        __syncthreads();

        half8 af[4], bf[4];
#pragma unroll
        for (int f = 0; f < 4; f++) {
            af[f] = *(const half8*)&As[(wm * 64 + f * 16 + lr) * TS + lk * 8];
            bf[f] = *(const half8*)&Bs[(wn * 64 + f * 16 + lr) * TS + lk * 8];
        }
#pragma unroll
        for (int fm = 0; fm < 4; fm++)
#pragma unroll
            for (int fn = 0; fn < 4; fn++)
                acc[fm][fn] = __builtin_amdgcn_mfma_f32_16x16x32_f16(
                    af[fm], bf[fn], acc[fm][fn], 0, 0, 0);
    }

    // epilogue: C/D map row=(lane>>4)*4+j, col=lane&15  [m89-verified]
#pragma unroll
    for (int fm = 0; fm < 4; fm++) {
#pragma unroll
        for (int fn = 0; fn < 4; fn++) {
#pragma unroll
            for (int j = 0; j < 4; j++) {
                const int gm = m0 + wm * 64 + fm * 16 + lk * 4 + j;
                const int gn = n0 + wn * 64 + fn * 16 + lr;
                if (gn >= N) continue;
                float a = acc[fm][fn][j];
                if (epi == 1) {
                    a = tanhf(a);
                    ((__half*)Cv)[(size_t)gm * ldc + gn] = __float2half(a);
                } else if (epi == 2) {
                    a += bias[gn];
                    const float xv = X[(size_t)gm * 1024 + gn];
                    float xp = 0.f;
                    if (gm & (T - 1)) xp = X[(size_t)(gm - 1) * 1024 + gn];
                    ((__half*)Cv)[(size_t)gm * ldc + gn] =
                        __float2half(xv + (xp - xv) * a);
                } else if (epi == 3) {
                    a += bias[gn];
                    ((__half*)Cv)[(size_t)gm * ldc + gn] = __float2half(a);
                } else if (epi == 4) {
                    ((float*)Cv)[(size_t)gm * ldc + gn] = a;
                } else {
                    ((__half*)Cv)[(size_t)gm * ldc + gn] = __float2half(a);
                }
            }
        }
    }
}

// ---------------- prepass: pack E = {r,k,dec} + ru --------------------------
// E layout: [b,h,t,k] entries of 8B {u32 rk(lo=r,hi=k), f32 dec}
__global__ __launch_bounds__(256) void k_prep(
    const __half* __restrict__ R, const __half* __restrict__ Kk,
    const __half* __restrict__ W, const float* __restrict__ bonus,
    uint4* __restrict__ E4, float* __restrict__ RU, int T)
{
    const int tok = blockIdx.x;
    const int b = tok >> 11, t = tok & (2048 - 1);
    const int h = threadIdx.x >> 6, lane = threadIdx.x & 63;
    const size_t base = (size_t)tok * 512 + h * 128 + 2 * lane;
    const unsigned rr = *(const unsigned*)(R + base);
    const unsigned kk = *(const unsigned*)(Kk + base);
    const unsigned ww = *(const unsigned*)(W + base);
    const float2 rf = up2(rr), kf = up2(kk), wf = up2(ww);
    const float d0 = __expf(-__expf(wf.x));
    const float d1 = __expf(-__expf(wf.y));
    const float2 uf = *(const float2*)(bonus + h * 128 + 2 * lane);
    float ru = rf.x * uf.x * kf.x + rf.y * uf.y * kf.y;
#pragma unroll
    for (int off = 1; off < 64; off <<= 1) ru += __shfl_xor(ru, off);
    const size_t eidx = ((size_t)(b * 4 + h) * T + t) * 64 + lane;  // uint4 units
    uint4 e;
    e.x = (rr & 0xFFFFu) | ((kk & 0xFFFFu) << 16);
    e.y = __float_as_uint(d0);
    e.z = (rr >> 16) | (kk & 0xFFFF0000u);
    e.w = __float_as_uint(d1);
    E4[eidx] = e;
    if (lane == 0) RU[(size_t)(b * 4 + h) * T + t] = ru;
}

// ---------------- scan: 1 wave/block, no barriers ---------------------------
// block = (b, h, vs of 8 v-cols). lane = (v = l>>3, kg = l&7), k = kg*16+j.
__global__ __launch_bounds__(64) void rwkv_scan(
    const uint2* __restrict__ E, const __half* __restrict__ V,
    const float* __restrict__ RU, __half* __restrict__ O, int T)
{
    const int bid = blockIdx.x;
    const int b = bid >> 7, h = (bid >> 5) & 3, vs = bid & 31;
    const int lane = threadIdx.x;
    const int v = lane >> 3, kg = lane & 7;

    const uint2* Ep = E + (size_t)(b * 4 + h) * T * 128 + kg * 16;
    const float* RUp = RU + (size_t)(b * 4 + h) * T;
    const __half* Vp = V + (size_t)b * T * 1024 + h * 256 + vs * 8 + v;
    __half* Op = O + (size_t)b * T * 1024 + h * 256 + vs * 8 + v;

    float S[16];
#pragma unroll
    for (int j = 0; j < 16; j++) S[j] = 0.f;

    uint2 ec[16];
#pragma unroll
    for (int j = 0; j < 16; j++) ec[j] = Ep[j];
    float vvc = __half2float(Vp[0]);
    float ruc = RUp[0];

    for (int t = 0; t < T; ++t) {
        uint2 en[16];
        float vvn = 0.f, run = 0.f;
        if (t + 1 < T) {
            const uint2* ebase = Ep + (size_t)(t + 1) * 128;
#pragma unroll
            for (int j = 0; j < 16; j++) en[j] = ebase[j];
            vvn = __half2float(Vp[(size_t)(t + 1) * 1024]);
            run = RUp[t + 1];
        }
        float osum = 0.f;
#pragma unroll
        for (int j = 0; j < 16; j++) {
            const float2 rk = up2(ec[j].x);
            const float dec = __uint_as_float(ec[j].y);
            osum = fmaf(rk.x, S[j], osum);
            S[j] = fmaf(dec, S[j], rk.y * vvc);
        }
        osum += __shfl_xor(osum, 1);
        osum += __shfl_xor(osum, 2);
        osum += __shfl_xor(osum, 4);
        if (kg == 0) Op[(size_t)t * 1024] = __float2half(osum + ruc * vvc);
#pragma unroll
        for (int j = 0; j < 16; j++) ec[j] = en[j];
        vvc = vvn; ruc = run;
    }
}

// ---------------- groupnorm + silu gate (f16 in/out) ------------------------
__global__ __launch_bounds__(256) void gn_gate(
    const __half* __restrict__ Obuf, const __half* __restrict__ G,
    const float* __restrict__ gnw, const float* __restrict__ gnb,
    __half* __restrict__ Y)
{
    const int token = blockIdx.x;
    const int wave = threadIdx.x >> 6, lane = threadIdx.x & 63;
    const size_t base = (size_t)token * 1024 + wave * 256 + lane * 4;
    const ushort4 xu = *(const ushort4*)(Obuf + base);
    const float x0 = hbits2f(xu.x), x1 = hbits2f(xu.y),
                x2 = hbits2f(xu.z), x3 = hbits2f(xu.w);
    float sum = x0 + x1 + x2 + x3;
    float ssq = x0 * x0 + x1 * x1 + x2 * x2 + x3 * x3;
#pragma unroll
    for (int off = 32; off >= 1; off >>= 1) {
        sum += __shfl_xor(sum, off);
        ssq += __shfl_xor(ssq, off);
    }
    const float mean = sum * (1.f / 256.f);
    const float var = ssq * (1.f / 256.f) - mean * mean;
    const float rstd = rsqrtf(var + 1e-5f);
    const int c0 = wave * 256 + lane * 4;
    const float4 w4 = *(const float4*)(gnw + c0);
    const float4 b4 = *(const float4*)(gnb + c0);
    const ushort4 gu = *(const ushort4*)(G + base);
    const float g0 = hbits2f(gu.x), g1 = hbits2f(gu.y),
                g2 = hbits2f(gu.z), g3 = hbits2f(gu.w);
    ushort4 y;
    y.x = f2h(((x0 - mean) * rstd * w4.x + b4.x) * (g0 / (1.f + __expf(-g0))));
    y.y = f2h(((x1 - mean) * rstd * w4.y + b4.y) * (g1 / (1.f + __expf(-g1))));
    y.z = f2h(((x2 - mean) * rstd * w4.z + b4.z) * (g2 / (1.f + __expf(-g2))));
    y.w = f2h(((x3 - mean) * rstd * w4.w + b4.w) * (g3 / (1.f + __expf(-g3))));
    *(ushort4*)(Y + base) = y;
}

// ---------------------------------------------------------------------------
extern "C" void kernel_launch(void* const* d_in, const int* in_sizes, int n_in,
                              void* d_out, int out_size, void* d_ws, size_t ws_size,
                              hipStream_t stream)
{
    (void)in_sizes; (void)n_in; (void)out_size; (void)ws_size;
    const float* x      = (const float*)d_in[0];
    const float* mu_x   = (const float*)d_in[1];
    const float* W_x1   = (const float*)d_in[2];
    const float* W_x2   = (const float*)d_in[3];
    const float* x_bias = (const float*)d_in[4];
    const float* W_r    = (const float*)d_in[5];
    const float* W_k    = (const float*)d_in[6];
    const float* W_v    = (const float*)d_in[7];
    const float* W_g    = (const float*)d_in[8];
    const float* A_w    = (const float*)d_in[9];
    const float* B_w    = (const float*)d_in[10];
    const float* b_w    = (const float*)d_in[11];
    const float* bonus  = (const float*)d_in[12];
    const float* gnw    = (const float*)d_in[13];
    const float* gnb    = (const float*)d_in[14];
    const float* W_o    = (const float*)d_in[15];

    const int B = 8, T = 2048, M = B * T;

    // ---- d_out as f16 scratch: [xw_h 32MB | inb_h 32MB], later E (64MB) ----
    __half* xwh  = (__half*)d_out;
    __half* inbh = xwh + (size_t)M * 1024;

    // ---- ws layout (halfs unless noted) ----
    __half* z   = (__half*)d_ws;                    // M*160
    __half* w1  = z   + (size_t)M * 160;            // M*64
    __half* rs  = w1  + (size_t)M * 64;             // M*512
    __half* ks  = rs  + (size_t)M * 512;            // M*512
    __half* wsm = ks  + (size_t)M * 512;            // M*512 (w stream)
    __half* vs  = wsm + (size_t)M * 512;            // M*1024
    __half* gs  = vs  + (size_t)M * 1024;           // M*1024
    float*  ru  = (float*)(gs + (size_t)M * 1024);  // 32*T f32
    __half* wgt = (__half*)(ru + (size_t)32 * T);   // f16 weights
    __half* oh  = rs;                               // overlay: o f16 M*1024 (r+k dead)
    __half* yb  = wsm;                              // overlay: y f16 M*1024 (w+v dead)

    __half* W_x1h = wgt;                 // 160*1024
    __half* W_x2h = W_x1h + 163840;      // 1024*160
    __half* W_rh  = W_x2h + 163840;      // 512*1024
    __half* W_kh  = W_rh + 524288;
    __half* W_vh  = W_kh + 524288;       // 1024*1024
    __half* W_gh  = W_vh + 1048576;
    __half* A_wh  = W_gh + 1048576;      // 64*1024
    __half* B_wh  = A_wh + 65536;        // 512*64
    __half* W_oh  = B_wh + 32768;        // 1024*1024

    const dim3 blk(256);
    auto cgrid = [](int n) { return dim3((n / 4 + 255) / 256); };
    cast16<<<cgrid(163840), blk, 0, stream>>>(W_x1, W_x1h, 163840 / 4);
    cast16<<<cgrid(163840), blk, 0, stream>>>(W_x2, W_x2h, 163840 / 4);
    cast16<<<cgrid(524288), blk, 0, stream>>>(W_r, W_rh, 524288 / 4);
    cast16<<<cgrid(524288), blk, 0, stream>>>(W_k, W_kh, 524288 / 4);
    cast16<<<cgrid(1048576), blk, 0, stream>>>(W_v, W_vh, 1048576 / 4);
    cast16<<<cgrid(1048576), blk, 0, stream>>>(W_g, W_gh, 1048576 / 4);
    cast16<<<cgrid(65536), blk, 0, stream>>>(A_w, A_wh, 65536 / 4);
    cast16<<<cgrid(32768), blk, 0, stream>>>(B_w, B_wh, 32768 / 4);
    cast16<<<cgrid(1048576), blk, 0, stream>>>(W_o, W_oh, 1048576 / 4);

    // 1. xw = lerp(x, mu_x) -> f16 (d_out lo)
    k_xw_h<<<(M * 256 + 255) / 256, blk, 0, stream>>>(x, mu_x, xwh, M, T);

    auto ggrid = [&](int N) { return dim3((N + 127) / 128, M / 128); };

    // 2. z = tanh(xw @ W_x1^T)
    gemm16<<<ggrid(160), blk, 0, stream>>>(xwh, 1024, W_x1h, 1024, z, 160,
                                           M, 160, 1024, nullptr, 1, nullptr, T);

    // 3. branches
    for (int n = 0; n < 5; ++n) {
        gemm16<<<ggrid(1024), blk, 0, stream>>>(z + n * 32, 160, W_x2h + n * 32, 160,
                                                inbh, 1024, M, 1024, 32,
                                                x_bias + n * 1024, 2, x, T);
        if (n == 1) {
            gemm16<<<ggrid(64), blk, 0, stream>>>(inbh, 1024, A_wh, 1024, w1, 64,
                                                  M, 64, 1024, nullptr, 1, nullptr, T);
            gemm16<<<ggrid(512), blk, 0, stream>>>(w1, 64, B_wh, 64, wsm, 512,
                                                   M, 512, 64, b_w, 3, nullptr, T);
        } else {
            __half* Cp = (n == 0) ? rs : (n == 2) ? ks : (n == 3) ? vs : gs;
            const __half* Wp = (n == 0) ? W_rh : (n == 2) ? W_kh : (n == 3) ? W_vh : W_gh;
            const int N = (n == 0 || n == 2) ? 512 : 1024;
            gemm16<<<ggrid(N), blk, 0, stream>>>(inbh, 1024, Wp, 1024, Cp, N,
                                                 M, N, 1024, nullptr, 0, nullptr, T);
        }
    }

    // 4. prepass -> E (all of d_out; xwh/inbh dead), ru
    k_prep<<<dim3(M), blk, 0, stream>>>(rs, ks, wsm, bonus,
                                        (uint4*)d_out, ru, T);

    // 5. scan -> o f16 (overlay on r+k region)
    rwkv_scan<<<dim3(1024), dim3(64), 0, stream>>>((const uint2*)d_out, vs, ru, oh, T);

    // 6. groupnorm + gate -> yb f16 (overlay on w+v region)
    gn_gate<<<dim3(M), blk, 0, stream>>>(oh, gs, gnw, gnb, yb);

    // 7. out = y @ W_o^T -> d_out f32 (E dead)
    gemm16<<<ggrid(1024), blk, 0, stream>>>(yb, 1024, W_oh, 1024, d_out, 1024,
                                            M, 1024, 1024, nullptr, 4, nullptr, T);
}

// Round 5
// 2490.817 us; speedup vs baseline: 2.0599x; 1.2044x over previous
//
#include <hip/hip_runtime.h>
#include <hip/hip_bf16.h>
#include <hip/hip_fp16.h>
#include <cstdint>

// ---------------------------------------------------------------------------
// RWKV6 attention: f16-MFMA GEMMs + barrier-free register-state scan.
//   Round 5: XCD-aware swizzle (scan + gemm), 2-deep scan pipeline (A/B regs).
//   d_out rotates: [xw_h | inb_h] (f16) -> E (packed scan input) -> final f32.
//   ws: z,w1,r,k,w,v,g (f16), ru (f32), f16 weight copies; o_h/yb overlay
//   dead stream regions.
// ---------------------------------------------------------------------------

typedef _Float16 half8 __attribute__((ext_vector_type(8)));
typedef float f32x4 __attribute__((ext_vector_type(4)));
typedef unsigned short ushort8 __attribute__((ext_vector_type(8)));

__device__ __forceinline__ float hbits2f(unsigned short us) {
    __half h; *reinterpret_cast<unsigned short*>(&h) = us; return __half2float(h);
}
__device__ __forceinline__ unsigned short f2h(float f) {
    __half h = __float2half(f);
    return *reinterpret_cast<unsigned short*>(&h);
}
__device__ __forceinline__ float2 up2(unsigned int u) {
    return make_float2(hbits2f((unsigned short)(u & 0xFFFF)),
                       hbits2f((unsigned short)(u >> 16)));
}

// ---------------- generic f32 -> f16 cast (weights) -------------------------
__global__ void cast16(const float* __restrict__ src, __half* __restrict__ dst, int n4)
{
    const int i = blockIdx.x * blockDim.x + threadIdx.x;
    if (i >= n4) return;
    const float4 f = *(const float4*)(src + (size_t)i * 4);
    ushort4 u;
    u.x = f2h(f.x); u.y = f2h(f.y); u.z = f2h(f.z); u.w = f2h(f.w);
    *(ushort4*)(dst + (size_t)i * 4) = u;
}

// ---------------- token shift (f16 out) -------------------------------------
__global__ void k_xw_h(const float* __restrict__ X, const float* __restrict__ mu,
                       __half* __restrict__ XW, int M, int T)
{
    const size_t i4 = (size_t)blockIdx.x * blockDim.x + threadIdx.x;
    if (i4 >= (size_t)M * 256) return;
    const size_t idx = i4 * 4;
    const int m = (int)(idx >> 10);
    const int d = (int)(idx & 1023);
    const int t = m & (T - 1);
    const float4 xv = *(const float4*)(X + idx);
    const float4 m4 = *(const float4*)(mu + d);
    float4 xp = make_float4(0.f, 0.f, 0.f, 0.f);
    if (t > 0) xp = *(const float4*)(X + idx - 1024);
    ushort4 o;
    o.x = f2h(xv.x + (xp.x - xv.x) * m4.x);
    o.y = f2h(xv.y + (xp.y - xv.y) * m4.y);
    o.z = f2h(xv.z + (xp.z - xv.z) * m4.z);
    o.w = f2h(xv.w + (xp.w - xv.w) * m4.w);
    *(ushort4*)(XW + idx) = o;
}

// ---------------- f16 MFMA GEMM: C[M,N] = A[M,K] @ B[N,K]^T -----------------
// epi: 0 f16 plain, 1 f16 tanh, 2 f16 bias+delta-lerp(X), 3 f16 bias, 4 f32 plain
#define TS 40  // LDS row stride in halfs (padded from 32)

__global__ __launch_bounds__(256) void gemm16(
    const __half* __restrict__ A, int lda,
    const __half* __restrict__ B, int ldb,
    void* __restrict__ Cv, int ldc,
    int M, int N, int K,
    const float* __restrict__ bias, int epi,
    const float* __restrict__ X, int T)
{
    __shared__ __align__(16) _Float16 As[128 * TS];
    __shared__ __align__(16) _Float16 Bs[128 * TS];

    const int tid = threadIdx.x;

    // XCD-aware swizzle: consecutive logical blocks (same A-row panel) on one XCD
    const int nwg = gridDim.x * gridDim.y;
    int p = blockIdx.y * gridDim.x + blockIdx.x;
    if (!(nwg & 7)) p = (p & 7) * (nwg >> 3) + (p >> 3);
    const int bx = p % gridDim.x, by = p / gridDim.x;

    const int m0 = by * 128;
    const int n0 = bx * 128;
    const int wave = tid >> 6, lane = tid & 63;
    const int wm = wave >> 1, wn = wave & 1;
    const int lr = lane & 15, lk = lane >> 4;

    const int srow = tid >> 1;          // 0..127
    const int sseg = (tid & 1) * 16;    // 0 or 16 halfs

    f32x4 acc[4][4] = {};

    for (int k0 = 0; k0 < K; k0 += 32) {
        // global loads (regs)
        const __half* ap = A + (size_t)(m0 + srow) * lda + k0 + sseg;
        ushort8 a0 = *(const ushort8*)ap;
        ushort8 a1 = *(const ushort8*)(ap + 8);
        ushort8 b0 = {0,0,0,0,0,0,0,0}, b1 = {0,0,0,0,0,0,0,0};
        if (n0 + srow < N) {
            const __half* bp = B + (size_t)(n0 + srow) * ldb + k0 + sseg;
            b0 = *(const ushort8*)bp;
            b1 = *(const ushort8*)(bp + 8);
        }
        __syncthreads();
        *(ushort8*)&As[srow * TS + sseg + 0] = a0;
        *(ushort8*)&As[srow * TS + sseg + 8] = a1;
        *(ushort8*)&Bs[srow * TS + sseg + 0] = b0;
        *(ushort8*)&Bs[srow * TS + sseg + 8] = b1;
        __syncthreads();

        half8 af[4], bf[4];
#pragma unroll
        for (int f = 0; f < 4; f++) {
            af[f] = *(const half8*)&As[(wm * 64 + f * 16 + lr) * TS + lk * 8];
            bf[f] = *(const half8*)&Bs[(wn * 64 + f * 16 + lr) * TS + lk * 8];
        }
#pragma unroll
        for (int fm = 0; fm < 4; fm++)
#pragma unroll
            for (int fn = 0; fn < 4; fn++)
                acc[fm][fn] = __builtin_amdgcn_mfma_f32_16x16x32_f16(
                    af[fm], bf[fn], acc[fm][fn], 0, 0, 0);
    }

    // epilogue: C/D map row=(lane>>4)*4+j, col=lane&15  [m89-verified]
#pragma unroll
    for (int fm = 0; fm < 4; fm++) {
#pragma unroll
        for (int fn = 0; fn < 4; fn++) {
#pragma unroll
            for (int j = 0; j < 4; j++) {
                const int gm = m0 + wm * 64 + fm * 16 + lk * 4 + j;
                const int gn = n0 + wn * 64 + fn * 16 + lr;
                if (gn >= N) continue;
                float a = acc[fm][fn][j];
                if (epi == 1) {
                    a = tanhf(a);
                    ((__half*)Cv)[(size_t)gm * ldc + gn] = __float2half(a);
                } else if (epi == 2) {
                    a += bias[gn];
                    const float xv = X[(size_t)gm * 1024 + gn];
                    float xp = 0.f;
                    if (gm & (T - 1)) xp = X[(size_t)(gm - 1) * 1024 + gn];
                    ((__half*)Cv)[(size_t)gm * ldc + gn] =
                        __float2half(xv + (xp - xv) * a);
                } else if (epi == 3) {
                    a += bias[gn];
                    ((__half*)Cv)[(size_t)gm * ldc + gn] = __float2half(a);
                } else if (epi == 4) {
                    ((float*)Cv)[(size_t)gm * ldc + gn] = a;
                } else {
                    ((__half*)Cv)[(size_t)gm * ldc + gn] = __float2half(a);
                }
            }
        }
    }
}

// ---------------- prepass: pack E = {r,k,dec} + ru --------------------------
// E layout: [b,h,t,k] entries of 8B {u32 rk(lo=r,hi=k), f32 dec}
__global__ __launch_bounds__(256) void k_prep(
    const __half* __restrict__ R, const __half* __restrict__ Kk,
    const __half* __restrict__ W, const float* __restrict__ bonus,
    uint4* __restrict__ E4, float* __restrict__ RU, int T)
{
    const int tok = blockIdx.x;
    const int b = tok >> 11, t = tok & (2048 - 1);
    const int h = threadIdx.x >> 6, lane = threadIdx.x & 63;
    const size_t base = (size_t)tok * 512 + h * 128 + 2 * lane;
    const unsigned rr = *(const unsigned*)(R + base);
    const unsigned kk = *(const unsigned*)(Kk + base);
    const unsigned ww = *(const unsigned*)(W + base);
    const float2 rf = up2(rr), kf = up2(kk), wf = up2(ww);
    const float d0 = __expf(-__expf(wf.x));
    const float d1 = __expf(-__expf(wf.y));
    const float2 uf = *(const float2*)(bonus + h * 128 + 2 * lane);
    float ru = rf.x * uf.x * kf.x + rf.y * uf.y * kf.y;
#pragma unroll
    for (int off = 1; off < 64; off <<= 1) ru += __shfl_xor(ru, off);
    const size_t eidx = ((size_t)(b * 4 + h) * T + t) * 64 + lane;  // uint4 units
    uint4 e;
    e.x = (rr & 0xFFFFu) | ((kk & 0xFFFFu) << 16);
    e.y = __float_as_uint(d0);
    e.z = (rr >> 16) | (kk & 0xFFFF0000u);
    e.w = __float_as_uint(d1);
    E4[eidx] = e;
    if (lane == 0) RU[(size_t)(b * 4 + h) * T + t] = ru;
}

// ---------------- scan: 1 wave/block, no barriers, 2-deep pipeline ----------
// logical block = (b, h, vs of 8 v-cols). lane = (v = l>>3, kg = l&7).
// XCD swizzle: all 32 blocks of one (b,h) land on the same XCD -> E served
// from that XCD's L2 instead of 8x-duplicated HBM streams.
__global__ __launch_bounds__(64) void rwkv_scan(
    const uint2* __restrict__ E, const __half* __restrict__ V,
    const float* __restrict__ RU, __half* __restrict__ O, int T)
{
    const int p = blockIdx.x;
    const int l = (p & 7) * 128 + (p >> 3);   // bijective, 1024 blocks
    const int b = l >> 7, h = (l >> 5) & 3, vs = l & 31;
    const int lane = threadIdx.x;
    const int v = lane >> 3, kg = lane & 7;

    const uint2* Ep = E + (size_t)(b * 4 + h) * T * 128 + kg * 16;
    const float* RUp = RU + (size_t)(b * 4 + h) * T;
    const __half* Vp = V + (size_t)b * T * 1024 + h * 256 + vs * 8 + v;
    __half* Op = O + (size_t)b * T * 1024 + h * 256 + vs * 8 + v;

    float S[16];
#pragma unroll
    for (int j = 0; j < 16; j++) S[j] = 0.f;

    uint2 eA[16], eB[16];
    float vA, vB, ruA, ruB;
#pragma unroll
    for (int j = 0; j < 16; j++) eA[j] = Ep[j];
#pragma unroll
    for (int j = 0; j < 16; j++) eB[j] = Ep[128 + j];
    vA = __half2float(Vp[0]);
    vB = __half2float(Vp[1024]);
    ruA = RUp[0];
    ruB = RUp[1];

    for (int t = 0; t < T; t += 2) {
        // ---- step t (buffer A) ----
        {
            float osum = 0.f;
#pragma unroll
            for (int j = 0; j < 16; j++) {
                const float2 rk = up2(eA[j].x);
                const float dec = __uint_as_float(eA[j].y);
                osum = fmaf(rk.x, S[j], osum);
                S[j] = fmaf(dec, S[j], rk.y * vA);
            }
            osum += __shfl_xor(osum, 1);
            osum += __shfl_xor(osum, 2);
            osum += __shfl_xor(osum, 4);
            if (kg == 0) Op[(size_t)t * 1024] = __float2half(osum + ruA * vA);
        }
        // ---- refill A <- t+2 ----
        if (t + 2 < T) {
            const uint2* eb = Ep + (size_t)(t + 2) * 128;
#pragma unroll
            for (int j = 0; j < 16; j++) eA[j] = eb[j];
            vA = __half2float(Vp[(size_t)(t + 2) * 1024]);
            ruA = RUp[t + 2];
        }
        // ---- step t+1 (buffer B) ----
        {
            float osum = 0.f;
#pragma unroll
            for (int j = 0; j < 16; j++) {
                const float2 rk = up2(eB[j].x);
                const float dec = __uint_as_float(eB[j].y);
                osum = fmaf(rk.x, S[j], osum);
                S[j] = fmaf(dec, S[j], rk.y * vB);
            }
            osum += __shfl_xor(osum, 1);
            osum += __shfl_xor(osum, 2);
            osum += __shfl_xor(osum, 4);
            if (kg == 0) Op[(size_t)(t + 1) * 1024] = __float2half(osum + ruB * vB);
        }
        // ---- refill B <- t+3 ----
        if (t + 3 < T) {
            const uint2* eb = Ep + (size_t)(t + 3) * 128;
#pragma unroll
            for (int j = 0; j < 16; j++) eB[j] = eb[j];
            vB = __half2float(Vp[(size_t)(t + 3) * 1024]);
            ruB = RUp[t + 3];
        }
    }
}

// ---------------- groupnorm + silu gate (f16 in/out) ------------------------
__global__ __launch_bounds__(256) void gn_gate(
    const __half* __restrict__ Obuf, const __half* __restrict__ G,
    const float* __restrict__ gnw, const float* __restrict__ gnb,
    __half* __restrict__ Y)
{
    const int token = blockIdx.x;
    const int wave = threadIdx.x >> 6, lane = threadIdx.x & 63;
    const size_t base = (size_t)token * 1024 + wave * 256 + lane * 4;
    const ushort4 xu = *(const ushort4*)(Obuf + base);
    const float x0 = hbits2f(xu.x), x1 = hbits2f(xu.y),
                x2 = hbits2f(xu.z), x3 = hbits2f(xu.w);
    float sum = x0 + x1 + x2 + x3;
    float ssq = x0 * x0 + x1 * x1 + x2 * x2 + x3 * x3;
#pragma unroll
    for (int off = 32; off >= 1; off >>= 1) {
        sum += __shfl_xor(sum, off);
        ssq += __shfl_xor(ssq, off);
    }
    const float mean = sum * (1.f / 256.f);
    const float var = ssq * (1.f / 256.f) - mean * mean;
    const float rstd = rsqrtf(var + 1e-5f);
    const int c0 = wave * 256 + lane * 4;
    const float4 w4 = *(const float4*)(gnw + c0);
    const float4 b4 = *(const float4*)(gnb + c0);
    const ushort4 gu = *(const ushort4*)(G + base);
    const float g0 = hbits2f(gu.x), g1 = hbits2f(gu.y),
                g2 = hbits2f(gu.z), g3 = hbits2f(gu.w);
    ushort4 y;
    y.x = f2h(((x0 - mean) * rstd * w4.x + b4.x) * (g0 / (1.f + __expf(-g0))));
    y.y = f2h(((x1 - mean) * rstd * w4.y + b4.y) * (g1 / (1.f + __expf(-g1))));
    y.z = f2h(((x2 - mean) * rstd * w4.z + b4.z) * (g2 / (1.f + __expf(-g2))));
    y.w = f2h(((x3 - mean) * rstd * w4.w + b4.w) * (g3 / (1.f + __expf(-g3))));
    *(ushort4*)(Y + base) = y;
}

// ---------------------------------------------------------------------------
extern "C" void kernel_launch(void* const* d_in, const int* in_sizes, int n_in,
                              void* d_out, int out_size, void* d_ws, size_t ws_size,
                              hipStream_t stream)
{
    (void)in_sizes; (void)n_in; (void)out_size; (void)ws_size;
    const float* x      = (const float*)d_in[0];
    const float* mu_x   = (const float*)d_in[1];
    const float* W_x1   = (const float*)d_in[2];
    const float* W_x2   = (const float*)d_in[3];
    const float* x_bias = (const float*)d_in[4];
    const float* W_r    = (const float*)d_in[5];
    const float* W_k    = (const float*)d_in[6];
    const float* W_v    = (const float*)d_in[7];
    const float* W_g    = (const float*)d_in[8];
    const float* A_w    = (const float*)d_in[9];
    const float* B_w    = (const float*)d_in[10];
    const float* b_w    = (const float*)d_in[11];
    const float* bonus  = (const float*)d_in[12];
    const float* gnw    = (const float*)d_in[13];
    const float* gnb    = (const float*)d_in[14];
    const float* W_o    = (const float*)d_in[15];

    const int B = 8, T = 2048, M = B * T;

    // ---- d_out as f16 scratch: [xw_h 32MB | inb_h 32MB], later E (64MB) ----
    __half* xwh  = (__half*)d_out;
    __half* inbh = xwh + (size_t)M * 1024;

    // ---- ws layout (halfs unless noted) ----
    __half* z   = (__half*)d_ws;                    // M*160
    __half* w1  = z   + (size_t)M * 160;            // M*64
    __half* rs  = w1  + (size_t)M * 64;             // M*512
    __half* ks  = rs  + (size_t)M * 512;            // M*512
    __half* wsm = ks  + (size_t)M * 512;            // M*512 (w stream)
    __half* vs  = wsm + (size_t)M * 512;            // M*1024
    __half* gs  = vs  + (size_t)M * 1024;           // M*1024
    float*  ru  = (float*)(gs + (size_t)M * 1024);  // 32*T f32
    __half* wgt = (__half*)(ru + (size_t)32 * T);   // f16 weights
    __half* oh  = rs;                               // overlay: o f16 M*1024 (r+k dead)
    __half* yb  = wsm;                              // overlay: y f16 M*1024 (w+v dead)

    __half* W_x1h = wgt;                 // 160*1024
    __half* W_x2h = W_x1h + 163840;      // 1024*160
    __half* W_rh  = W_x2h + 163840;      // 512*1024
    __half* W_kh  = W_rh + 524288;
    __half* W_vh  = W_kh + 524288;       // 1024*1024
    __half* W_gh  = W_vh + 1048576;
    __half* A_wh  = W_gh + 1048576;      // 64*1024
    __half* B_wh  = A_wh + 65536;        // 512*64
    __half* W_oh  = B_wh + 32768;        // 1024*1024

    const dim3 blk(256);
    auto cgrid = [](int n) { return dim3((n / 4 + 255) / 256); };
    cast16<<<cgrid(163840), blk, 0, stream>>>(W_x1, W_x1h, 163840 / 4);
    cast16<<<cgrid(163840), blk, 0, stream>>>(W_x2, W_x2h, 163840 / 4);
    cast16<<<cgrid(524288), blk, 0, stream>>>(W_r, W_rh, 524288 / 4);
    cast16<<<cgrid(524288), blk, 0, stream>>>(W_k, W_kh, 524288 / 4);
    cast16<<<cgrid(1048576), blk, 0, stream>>>(W_v, W_vh, 1048576 / 4);
    cast16<<<cgrid(1048576), blk, 0, stream>>>(W_g, W_gh, 1048576 / 4);
    cast16<<<cgrid(65536), blk, 0, stream>>>(A_w, A_wh, 65536 / 4);
    cast16<<<cgrid(32768), blk, 0, stream>>>(B_w, B_wh, 32768 / 4);
    cast16<<<cgrid(1048576), blk, 0, stream>>>(W_o, W_oh, 1048576 / 4);

    // 1. xw = lerp(x, mu_x) -> f16 (d_out lo)
    k_xw_h<<<(M * 256 + 255) / 256, blk, 0, stream>>>(x, mu_x, xwh, M, T);

    auto ggrid = [&](int N) { return dim3((N + 127) / 128, M / 128); };

    // 2. z = tanh(xw @ W_x1^T)
    gemm16<<<ggrid(160), blk, 0, stream>>>(xwh, 1024, W_x1h, 1024, z, 160,
                                           M, 160, 1024, nullptr, 1, nullptr, T);

    // 3. branches
    for (int n = 0; n < 5; ++n) {
        gemm16<<<ggrid(1024), blk, 0, stream>>>(z + n * 32, 160, W_x2h + n * 32, 160,
                                                inbh, 1024, M, 1024, 32,
                                                x_bias + n * 1024, 2, x, T);
        if (n == 1) {
            gemm16<<<ggrid(64), blk, 0, stream>>>(inbh, 1024, A_wh, 1024, w1, 64,
                                                  M, 64, 1024, nullptr, 1, nullptr, T);
            gemm16<<<ggrid(512), blk, 0, stream>>>(w1, 64, B_wh, 64, wsm, 512,
                                                   M, 512, 64, b_w, 3, nullptr, T);
        } else {
            __half* Cp = (n == 0) ? rs : (n == 2) ? ks : (n == 3) ? vs : gs;
            const __half* Wp = (n == 0) ? W_rh : (n == 2) ? W_kh : (n == 3) ? W_vh : W_gh;
            const int N = (n == 0 || n == 2) ? 512 : 1024;
            gemm16<<<ggrid(N), blk, 0, stream>>>(inbh, 1024, Wp, 1024, Cp, N,
                                                 M, N, 1024, nullptr, 0, nullptr, T);
        }
    }

    // 4. prepass -> E (all of d_out; xwh/inbh dead), ru
    k_prep<<<dim3(M), blk, 0, stream>>>(rs, ks, wsm, bonus,
                                        (uint4*)d_out, ru, T);

    // 5. scan -> o f16 (overlay on r+k region)
    rwkv_scan<<<dim3(1024), dim3(64), 0, stream>>>((const uint2*)d_out, vs, ru, oh, T);

    // 6. groupnorm + gate -> yb f16 (overlay on w+v region)
    gn_gate<<<dim3(M), blk, 0, stream>>>(oh, gs, gnw, gnb, yb);

    // 7. out = y @ W_o^T -> d_out f32 (E dead)
    gemm16<<<ggrid(1024), blk, 0, stream>>>(yb, 1024, W_oh, 1024, d_out, 1024,
                                            M, 1024, 1024, nullptr, 4, nullptr, T);
}